// Round 8
// baseline (121.711 us; speedup 1.0000x reference)
//
#include <hip/hip_runtime.h>
#include <cmath>

#define C_COLS 8192

struct NfArgs {
    float tbl[16];   // fp16-exact NF4 levels, as f32
    float kexp;      // -1.702 * log2(e) * qmax  (logistic index estimate)
};

// ---------------------------------------------------------------------------
// R8: DS-pipe diet. One workgroup (256 thr = 4 waves) per row; wave w owns
// floats [w*2048, w*2048+2048). Lane i owns 32 CONSECUTIVE floats
// [i*32, i*32+32) = half of quant-block (i>>1). Loads: 8 dwordx4 per lane,
// lane-stride 128 B (all lines fully consumed).
//   - block min/max: 62 VALU local + ONE xor-1 shuffle pair   (was 64 DS ops)
//   - row scale reduce: xor 2,4,8,16,32                        (10 DS ops)
//   - argmin window fetch: one ds_read_b128 from float4 qtbl   (was 3 b32)
// Decision arithmetic BIT-IDENTICAL to passing R5/R7:
//   x_norm: s2r = 2.0f/den (IEEE); p=(x-bm)*s2r; xn=p-1.0f (contract OFF)
//   argmin: logistic estimate ci (+-1-accurate) -> clamp [1,14] -> exact
//           3-candidate replay of the 16-way strict-'<' scan
//   scales: sq = rintf(((sc-s_min)*round32(1/sden))*255); srec = s_min +
//           sq/255.0f*srange  (IEEE divide kept)
// min/max reassociation is exact => identical bits everywhere.
// ---------------------------------------------------------------------------
__global__ __launch_bounds__(256) void nf4_main_kernel(
        const float* __restrict__ x, float* __restrict__ out, NfArgs args) {
#pragma clang fp contract(off)
    __shared__ float4 qtbl[16];            // {t[i-1], t[i], t[i+1], 0}
    __shared__ float  smin[4], smax[4];

    const int wave = threadIdx.x >> 6;
    const int lane = threadIdx.x & 63;
    const long base = (long)blockIdx.x * C_COLS + (long)wave * 2048;
    // lane owns float4s [lane*8, lane*8+8)
    const float4* __restrict__ xin4 = reinterpret_cast<const float4*>(x + base) + lane * 8;
    float4* __restrict__ out4       = reinterpret_cast<float4*>(out + base) + lane * 8;

    // issue all global loads first (8 outstanding dwordx4 per lane)
    float4 v[8];
#pragma unroll
    for (int k = 0; k < 8; ++k) v[k] = xin4[k];

    if (threadIdx.x < 16) {
        const int i = threadIdx.x;
        float4 q;
        q.x = args.tbl[(i > 0) ? i - 1 : 0];
        q.y = args.tbl[i];
        q.z = args.tbl[(i < 15) ? i + 1 : 15];
        q.w = 0.0f;
        qtbl[i] = q;
    }

    // ---- local min/max over the lane's 32 consecutive elems (exact) ----
    float m4[8], M4[8];
#pragma unroll
    for (int k = 0; k < 8; ++k) {
        m4[k] = fminf(fminf(v[k].x, v[k].y), fminf(v[k].z, v[k].w));
        M4[k] = fmaxf(fmaxf(v[k].x, v[k].y), fmaxf(v[k].z, v[k].w));
    }
    float m = m4[0], M = M4[0];
#pragma unroll
    for (int k = 1; k < 8; ++k) { m = fminf(m, m4[k]); M = fmaxf(M, M4[k]); }
    // combine the two half-blocks (lanes 2b, 2b+1) -> full 64-elem block
    m = fminf(m, __shfl_xor(m, 1));
    M = fmaxf(M, __shfl_xor(M, 1));
    const float bm_blk = m, bM_blk = M;
    const float sc     = bM_blk - bm_blk;              // exact; block-uniform

    // ---- row-level min/max of sc (wave part: xor 2..32; dup lanes harmless) ----
    float tmin = sc, tmax = sc;
#pragma unroll
    for (int off = 2; off < 64; off <<= 1) {
        tmin = fminf(tmin, __shfl_xor(tmin, off));
        tmax = fmaxf(tmax, __shfl_xor(tmax, off));
    }
    if (lane == 0) { smin[wave] = tmin; smax[wave] = tmax; }
    __syncthreads();                                   // covers qtbl + smin/smax

    const float s_min  = fminf(fminf(smin[0], smin[1]), fminf(smin[2], smin[3]));
    const float s_max  = fmaxf(fmaxf(smax[0], smax[1]), fmaxf(smax[2], smax[3]));
    const float srange = s_max - s_min;
    const float sden   = srange + 1e-8f;
    const float sqr    = 1.0f / sden;                  // broadcast recip hoist

    // ---- per-lane (block-uniform) scale double-quant + x_norm constants ----
    const float sq   = rintf(((sc - s_min) * sqr) * 255.0f);   // RNE = np.round
    const float sr   = s_min + sq / 255.0f * srange;           // IEEE /255
    const float den  = (bM_blk - bm_blk) + 1e-8f;
    const float s2r  = 2.0f / den;                     // == 2*round(1/den) exactly
    const float kexp = args.kexp;

#pragma unroll
    for (int k = 0; k < 8; ++k) {
        float xv[4] = { v[k].x, v[k].y, v[k].z, v[k].w };
        float wv[4];
#pragma unroll
        for (int c = 0; c < 4; ++c) {
            // exact R5 x_norm: recip-mul then SEPARATE subtract (no fma)
            float p  = (xv[c] - bm_blk) * s2r;
            float xn = p - 1.0f;
            // index estimate: 16*logistic(1.702*qmax*xn)  (+-1 accurate)
            float eb = __builtin_amdgcn_exp2f(xn * kexp);
            float f  = 16.0f * __builtin_amdgcn_rcpf(1.0f + eb);
            int ci = (int)f;
            ci = min(max(ci, 1), 14);
            // one b128 pulls the 3 candidates; exact replay of the scan
            float4 w3 = qtbl[ci];
            float a0 = fabsf(xn - w3.x);
            float a1 = fabsf(xn - w3.y);
            float a2 = fabsf(xn - w3.z);
            float t01  = (a1 < a0) ? w3.y : w3.x;      // strict <, index order
            float amin = fminf(a1, a0);
            float tsel = (a2 < amin) ? w3.z : t01;
            wv[c] = (tsel + 1.0f) * 0.5f * sr + bm_blk;  // mul+add, contract off
        }
        float4 r; r.x = wv[0]; r.y = wv[1]; r.z = wv[2]; r.w = wv[3];
        out4[k] = r;
    }
}

// ---------------------------------------------------------------------------
// Host-side table (input-independent, deterministic): f64 ndtri via A&S seed
// + 3 Newton steps on Phi (~1e-13, libm-variation-proof), f32 normalize,
// exact fp16 RNE via ulp-scaled rint. Same values as the passing R5-R7 path.
// ---------------------------------------------------------------------------
static void compute_nf_args(NfArgs* a) {
    double z[16];
    for (int i = 0; i < 16; ++i) {
        double p  = (2.0 * i + 1.0) / 32.0;
        double pl = (p < 0.5) ? p : 1.0 - p;
        double t  = std::sqrt(-2.0 * std::log(pl));
        double zz = t - (2.30753 + 0.27061 * t) / (1.0 + t * (0.99229 + 0.04481 * t));
        if (p < 0.5) zz = -zz;
        for (int it = 0; it < 3; ++it) {
            double Phi = 0.5 * std::erfc(-zz * 0.7071067811865476);
            double phi = 0.3989422804014326779 * std::exp(-0.5 * zz * zz);
            zz -= (Phi - p) / phi;
        }
        z[i] = zz;
    }
    float zf[16], qmax = 0.0f;
    for (int i = 0; i < 16; ++i) { zf[i] = (float)z[i]; qmax = std::fmax(qmax, std::fabs(zf[i])); }
    for (int i = 0; i < 16; ++i) {
        float qn = zf[i] / qmax;                       // IEEE f32 divide
        double av = std::fabs((double)qn);
        int e; std::frexp(av, &e);
        double ulp = std::ldexp(1.0, e - 11);
        a->tbl[i] = (float)std::copysign(std::rint(av / ulp) * ulp, (double)qn);
    }
    a->kexp = (float)(-1.702 * 1.4426950408889634 * (double)qmax);
}

extern "C" void kernel_launch(void* const* d_in, const int* in_sizes, int n_in,
                              void* d_out, int out_size, void* d_ws, size_t ws_size,
                              hipStream_t stream) {
    const float* x = (const float*)d_in[0];
    float* out     = (float*)d_out;
    const int rows = in_sizes[0] / C_COLS;

    NfArgs args;
    compute_nf_args(&args);                            // host CPU, deterministic

    nf4_main_kernel<<<rows, 256, 0, stream>>>(x, out, args);
}